// Round 2
// baseline (1798.869 us; speedup 1.0000x reference)
//
#include <hip/hip_runtime.h>
#include <math.h>

#define S_LEN 512
#define B_SZ  256

__device__ __forceinline__ float sigm(float x) { return 1.0f / (1.0f + __expf(-x)); }

// ---------------- pack: padded weight blocks + bias + w1 correct-col sums + h0 copy
__global__ void k_pack(const float* __restrict__ W1, const float* __restrict__ Wd,
                       const float* __restrict__ W2, const float* __restrict__ W3,
                       const float* __restrict__ W4, const float* __restrict__ b2,
                       const float* __restrict__ b3, const float* __restrict__ b4,
                       const float* __restrict__ h0,
                       float* __restrict__ Wld, float* __restrict__ Wz,
                       float* __restrict__ bz, float* __restrict__ w1csum,
                       float* __restrict__ hcarry, float* __restrict__ pred)
{
    int idx0 = blockIdx.x * blockDim.x + threadIdx.x;
    int stride = gridDim.x * blockDim.x;
    // Wld [256 out][256 in]: rows 0..127 -> W1[:, 0:256]; rows 128..255 -> [Wd | 0]
    for (int idx = idx0; idx < 256 * 256; idx += stride) {
        int c = idx >> 8, j = idx & 255;
        float v;
        if (c < 128) v = W1[c * 306 + j];
        else         v = (j < 128) ? Wd[(c - 128) * 128 + j] : 0.f;
        Wld[idx] = v;
    }
    // Wz [384 out][384 in]: A = [lp(0:128) | it(128:256) | le(256:384)]
    for (int idx = idx0; idx < 384 * 384; idx += stride) {
        int c = idx / 384, j = idx - c * 384;
        float v;
        if (c < 128)      v = W2[c * 512 + j];
        else if (c < 256) v = W3[(c - 128) * 512 + j];
        else              v = (j >= 128 && j < 256) ? W4[(c - 256) * 384 + 128 + j] : 0.f;
        Wz[idx] = v;
    }
    for (int idx = idx0; idx < 384; idx += stride)
        bz[idx] = (idx < 128) ? b2[idx] : (idx < 256 ? b3[idx - 128] : b4[idx - 256]);
    for (int idx = idx0; idx < 128; idx += stride) {
        float s = 0.f;
        for (int j = 0; j < 50; ++j) s += W1[idx * 306 + 256 + j];
        w1csum[idx] = s;
    }
    for (int idx = idx0; idx < 256 * 128; idx += stride) hcarry[idx] = h0[idx];
    for (int idx = idx0; idx < 256; idx += stride) pred[(size_t)idx * S_LEN] = 0.f;
}

// ---------------- GEMM 1 (chunked): learn (cb=0) + diff (cb=1) for s in [s_lo, s_hi)
// virtual row vr = (s - s_lo)*256 + b; output row = vr + out_row0 (time-major [s][b])
__global__ __launch_bounds__(256) void k_ld_gemm(
    const int* __restrict__ qseq, const int* __restrict__ utseq, const int* __restrict__ cseq,
    const float* __restrict__ Eq, const float* __restrict__ Eut,
    const float* __restrict__ Wld, const float* __restrict__ b1, const float* __restrict__ bd,
    const float* __restrict__ w1csum,
    float* __restrict__ learn_c, float* __restrict__ diff_c,
    int s_lo, int out_row0)
{
    __shared__ __align__(16) float At[64][72];    // [row][k]
    __shared__ __align__(16) float Wt[64][132];   // [k][col]
    const int tid = threadIdx.x;
    const int vr0 = blockIdx.x * 64;
    const int cb = blockIdx.y;       // 0: learn, 1: diff
    const int tx = tid & 31;
    const int ty = tid >> 5;
    float acc[8][4];
#pragma unroll
    for (int i = 0; i < 8; ++i)
#pragma unroll
        for (int j = 0; j < 4; ++j) acc[i][j] = 0.f;

    for (int k0 = 0; k0 < 256; k0 += 64) {
#pragma unroll
        for (int ld = 0; ld < 4; ++ld) {
            int flatq = tid + ld * 256;            // 0..1023
            int kq = flatq & 15, r = flatq >> 4;
            int vr = vr0 + r;
            int b = vr & 255, s = s_lo + (vr >> 8);
            int rin = b * S_LEN + s;
            int j = k0 + kq * 4;
            const float* src = (j < 128) ? (Eq + (size_t)qseq[rin] * 128 + j)
                                         : (Eut + (size_t)utseq[rin] * 128 + (j - 128));
            float4 v = *(const float4*)src;
            *(float4*)&At[r][kq * 4] = v;
        }
#pragma unroll
        for (int ld = 0; ld < 8; ++ld) {
            int flatq = tid + ld * 256;            // 0..2047
            int kq = flatq & 15, c = flatq >> 4;
            float4 v = *(const float4*)&Wld[(size_t)(cb * 128 + c) * 256 + k0 + kq * 4];
            Wt[kq * 4 + 0][c] = v.x; Wt[kq * 4 + 1][c] = v.y;
            Wt[kq * 4 + 2][c] = v.z; Wt[kq * 4 + 3][c] = v.w;
        }
        __syncthreads();
#pragma unroll
        for (int kq = 0; kq < 16; ++kq) {
            float4 a4[8];
#pragma unroll
            for (int i = 0; i < 8; ++i) a4[i] = *(const float4*)&At[ty * 8 + i][kq * 4];
#pragma unroll
            for (int kk = 0; kk < 4; ++kk) {
                float4 w4 = *(const float4*)&Wt[kq * 4 + kk][tx * 4];
#pragma unroll
                for (int i = 0; i < 8; ++i) {
                    float av = (kk == 0) ? a4[i].x : (kk == 1) ? a4[i].y : (kk == 2) ? a4[i].z : a4[i].w;
                    acc[i][0] = fmaf(av, w4.x, acc[i][0]);
                    acc[i][1] = fmaf(av, w4.y, acc[i][1]);
                    acc[i][2] = fmaf(av, w4.z, acc[i][2]);
                    acc[i][3] = fmaf(av, w4.w, acc[i][3]);
                }
            }
        }
        __syncthreads();
    }
    const int c = tx * 4;
    if (cb == 0) {
        float4 b1v = *(const float4*)&b1[c];
        float4 wcs = *(const float4*)&w1csum[c];
#pragma unroll
        for (int i = 0; i < 8; ++i) {
            int vr = vr0 + ty * 8 + i;
            int b = vr & 255, s = s_lo + (vr >> 8);
            float corr = (float)cseq[b * S_LEN + s];
            float4 o;
            o.x = acc[i][0] + corr * wcs.x + b1v.x;
            o.y = acc[i][1] + corr * wcs.y + b1v.y;
            o.z = acc[i][2] + corr * wcs.z + b1v.z;
            o.w = acc[i][3] + corr * wcs.w + b1v.w;
            *(float4*)&learn_c[(size_t)(vr + out_row0) * 128 + c] = o;
        }
    } else {
        float4 bdv = *(const float4*)&bd[c];
#pragma unroll
        for (int i = 0; i < 8; ++i) {
            int vr = vr0 + ty * 8 + i;
            float4 o;
            o.x = sigm(acc[i][0] + bdv.x);
            o.y = sigm(acc[i][1] + bdv.y);
            o.z = sigm(acc[i][2] + bdv.z);
            o.w = sigm(acc[i][3] + bdv.w);
            *(float4*)&diff_c[(size_t)(vr + out_row0) * 128 + c] = o;
        }
    }
}

// ---------------- disc: sigmoid(q . Wdisc + bdisc) * 10 (full sequence, once) -----
__global__ __launch_bounds__(256) void k_disc(const int* __restrict__ qseq,
                                              const float* __restrict__ Eq,
                                              const float* __restrict__ Wdisc,
                                              const float* __restrict__ bdisc,
                                              float* __restrict__ disc)
{
    __shared__ float wd[128];
    __shared__ float bds;
    if (threadIdx.x < 128) wd[threadIdx.x] = Wdisc[threadIdx.x];
    if (threadIdx.x == 0) bds = bdisc[0];
    __syncthreads();
    int r = blockIdx.x * 64 + (threadIdx.x >> 2);
    int q4 = threadIdx.x & 3;
    const float* qe = Eq + (size_t)qseq[r] * 128 + q4 * 32;
    float s = 0.f;
#pragma unroll
    for (int j = 0; j < 32; ++j) s = fmaf(qe[j], wd[q4 * 32 + j], s);
    s += __shfl_xor(s, 1, 64);
    s += __shfl_xor(s, 2, 64);
    if (q4 == 0) disc[r] = sigm(s + bds) * 10.0f;
}

// ---------------- GEMM 2 (chunked): U_c[lt*256+b, 0:384], t = t0+lt ---------------
// learn_c row for s=t-1 is exactly `ur`; for s=t it is `ur+256` (by layout).
__global__ __launch_bounds__(256) void k_u_gemm(
    const int* __restrict__ itseq, const float* __restrict__ Eit,
    const float* __restrict__ learn_c, const float* __restrict__ Wz,
    const float* __restrict__ bz, float* __restrict__ U_c, int t0)
{
    __shared__ __align__(16) float At[64][72];
    __shared__ __align__(16) float Wt[64][132];
    const int tid = threadIdx.x;
    const int ur0 = blockIdx.x * 64;
    const int cb = blockIdx.y;               // col block 0..2
    const int t = t0 + (ur0 >> 8);           // block-constant
    const int tx = tid & 31, ty = tid >> 5;
    float acc[8][4];
#pragma unroll
    for (int i = 0; i < 8; ++i)
#pragma unroll
        for (int j = 0; j < 4; ++j) acc[i][j] = 0.f;

    for (int k0 = 0; k0 < 384; k0 += 64) {
#pragma unroll
        for (int ld = 0; ld < 4; ++ld) {
            int flatq = tid + ld * 256;
            int kq = flatq & 15, r = flatq >> 4;
            int ur = ur0 + r;
            int b = ur & 255;
            int j = k0 + kq * 4;
            float4 v;
            if (j < 128) {
                if (t == 0) { v.x = v.y = v.z = v.w = 0.f; }
                else v = *(const float4*)&learn_c[(size_t)ur * 128 + j];
            } else if (j < 256) {
                int ii = itseq[b * S_LEN + t];
                v = *(const float4*)&Eit[(size_t)ii * 128 + (j - 128)];
            } else {
                v = *(const float4*)&learn_c[(size_t)(ur + 256) * 128 + (j - 256)];
            }
            *(float4*)&At[r][kq * 4] = v;
        }
#pragma unroll
        for (int ld = 0; ld < 8; ++ld) {
            int flatq = tid + ld * 256;
            int kq = flatq & 15, c = flatq >> 4;
            float4 v = *(const float4*)&Wz[(size_t)(cb * 128 + c) * 384 + k0 + kq * 4];
            Wt[kq * 4 + 0][c] = v.x; Wt[kq * 4 + 1][c] = v.y;
            Wt[kq * 4 + 2][c] = v.z; Wt[kq * 4 + 3][c] = v.w;
        }
        __syncthreads();
#pragma unroll
        for (int kq = 0; kq < 16; ++kq) {
            float4 a4[8];
#pragma unroll
            for (int i = 0; i < 8; ++i) a4[i] = *(const float4*)&At[ty * 8 + i][kq * 4];
#pragma unroll
            for (int kk = 0; kk < 4; ++kk) {
                float4 w4 = *(const float4*)&Wt[kq * 4 + kk][tx * 4];
#pragma unroll
                for (int i = 0; i < 8; ++i) {
                    float av = (kk == 0) ? a4[i].x : (kk == 1) ? a4[i].y : (kk == 2) ? a4[i].z : a4[i].w;
                    acc[i][0] = fmaf(av, w4.x, acc[i][0]);
                    acc[i][1] = fmaf(av, w4.y, acc[i][1]);
                    acc[i][2] = fmaf(av, w4.z, acc[i][2]);
                    acc[i][3] = fmaf(av, w4.w, acc[i][3]);
                }
            }
        }
        __syncthreads();
    }
    const int c = tx * 4;
    float4 bzv = *(const float4*)&bz[cb * 128 + c];
#pragma unroll
    for (int i = 0; i < 8; ++i) {
        int ur = ur0 + ty * 8 + i;
        float4 o;
        o.x = acc[i][0] + bzv.x;
        o.y = acc[i][1] + bzv.y;
        o.z = acc[i][2] + bzv.z;
        o.w = acc[i][3] + bzv.w;
        *(float4*)&U_c[(size_t)ur * 384 + cb * 128 + c] = o;
    }
}

// ---------------- scan (chunked): steps t = t0 .. t0+T_len-1, h carried in ws -----
__global__ __launch_bounds__(512, 2) void k_scan(
    const float* __restrict__ U_c, const float* __restrict__ diff_c,
    const float* __restrict__ disc, float* __restrict__ hcarry,
    const float* __restrict__ W2, const float* __restrict__ W3,
    const float* __restrict__ W4, const float* __restrict__ Wa,
    const float* __restrict__ ba, float* __restrict__ pred,
    int t0, int T_len)
{
    const int b = blockIdx.x;
    const int tid = threadIdx.x;
    const int k = tid >> 2;          // output element 0..127
    const int q = tid & 3;           // j-quarter
    const int j0 = q * 32;

    float w2h[32], w3h[32], w4h[32], w4l[32], wak[32];
    {
        const float* p2 = W2 + k * 512 + 384 + j0;
        const float* p3 = W3 + k * 512 + 384 + j0;
        const float* p4h = W4 + k * 384 + j0;
        const float* p4l = W4 + k * 384 + 128 + j0;
        const float* pa = Wa + k * 128 + j0;
#pragma unroll
        for (int jj = 0; jj < 32; ++jj) {
            w2h[jj] = p2[jj]; w3h[jj] = p3[jj]; w4h[jj] = p4h[jj];
            w4l[jj] = p4l[jj]; wak[jj] = pa[jj];
        }
    }
    const float bak = ba[k];

    __shared__ __align__(16) float hbuf[2][128];
    __shared__ __align__(16) float LGs[128];
    __shared__ __align__(16) float term[128];

    if (tid < 128) hbuf[0][tid] = hcarry[b * 128 + tid];
    __syncthreads();

    const float* grow = disc + (size_t)b * S_LEN;

    for (int lt = 0; lt < T_len; ++lt) {
        const int cur = lt & 1;
        const float* hp = hbuf[cur];
        const float* Ut = U_c + ((size_t)lt * B_SZ + b) * 384;
        float u2 = Ut[k];
        float u3 = Ut[128 + k];
        float u4 = Ut[256 + k];
        float dk = diff_c[((size_t)(lt + 2) * B_SZ + b) * 128 + k];
        float g = grow[t0 + lt + 1];

        // ---- stage 1: s2,s3,s4 = h_pre . {W2h,W3h,W4h}[k, j-range]
        float hr[32];
#pragma unroll
        for (int i = 0; i < 8; ++i) {
            float4 v = *(const float4*)&hp[j0 + i * 4];
            hr[i * 4 + 0] = v.x; hr[i * 4 + 1] = v.y; hr[i * 4 + 2] = v.z; hr[i * 4 + 3] = v.w;
        }
        float s2 = 0.f, s3 = 0.f, s4 = 0.f;
#pragma unroll
        for (int jj = 0; jj < 32; ++jj) {
            s2 = fmaf(hr[jj], w2h[jj], s2);
            s3 = fmaf(hr[jj], w3h[jj], s3);
            s4 = fmaf(hr[jj], w4h[jj], s4);
        }
        s2 += __shfl_xor(s2, 1, 64); s2 += __shfl_xor(s2, 2, 64);
        s3 += __shfl_xor(s3, 1, 64); s3 += __shfl_xor(s3, 2, 64);
        s4 += __shfl_xor(s4, 1, 64); s4 += __shfl_xor(s4, 2, 64);
        if (q == 0) {
            float gain = 2.f * sigm(2.f * (s2 + u2)) - 1.f;   // tanh
            float gl = sigm(s3 + u3);
            LGs[k] = gl * (gain + 1.f) * 0.5f;
        }
        __syncthreads();

        // ---- stage 2: gamma_f, h_new
        float lr[32];
#pragma unroll
        for (int i = 0; i < 8; ++i) {
            float4 v = *(const float4*)&LGs[j0 + i * 4];
            lr[i * 4 + 0] = v.x; lr[i * 4 + 1] = v.y; lr[i * 4 + 2] = v.z; lr[i * 4 + 3] = v.w;
        }
        float s4l = 0.f;
#pragma unroll
        for (int jj = 0; jj < 32; ++jj) s4l = fmaf(lr[jj], w4l[jj], s4l);
        s4l += __shfl_xor(s4l, 1, 64); s4l += __shfl_xor(s4l, 2, 64);
        if (q == 0) {
            float gf = sigm(s4 + s4l + u4);
            hbuf[cur ^ 1][k] = LGs[k] + gf * hp[k];
        }
        __syncthreads();

        // ---- stage 3: ability + per-channel term
        float hr2[32];
#pragma unroll
        for (int i = 0; i < 8; ++i) {
            float4 v = *(const float4*)&hbuf[cur ^ 1][j0 + i * 4];
            hr2[i * 4 + 0] = v.x; hr2[i * 4 + 1] = v.y; hr2[i * 4 + 2] = v.z; hr2[i * 4 + 3] = v.w;
        }
        float sa = 0.f;
#pragma unroll
        for (int jj = 0; jj < 32; ++jj) sa = fmaf(hr2[jj], wak[jj], sa);
        sa += __shfl_xor(sa, 1, 64); sa += __shfl_xor(sa, 2, 64);
        if (q == 0) {
            float ab = sigm(sa + bak);
            term[k] = (ab - dk) * dk;
        }
        __syncthreads();

        // ---- y reduction (wave 0)
        if (tid < 64) {
            float v = term[tid] + term[tid + 64];
            v += __shfl_xor(v, 32, 64);
            v += __shfl_xor(v, 16, 64);
            v += __shfl_xor(v, 8, 64);
            v += __shfl_xor(v, 4, 64);
            v += __shfl_xor(v, 2, 64);
            v += __shfl_xor(v, 1, 64);
            if (tid == 0) pred[(size_t)b * S_LEN + t0 + lt + 1] = sigm(g * v);
        }
    }
    __syncthreads();
    if (tid < 128) hcarry[b * 128 + tid] = hbuf[T_len & 1][tid];
}

extern "C" void kernel_launch(void* const* d_in, const int* in_sizes, int n_in,
                              void* d_out, int out_size, void* d_ws, size_t ws_size,
                              hipStream_t stream)
{
    const int*   qseq  = (const int*)d_in[0];
    const int*   itseq = (const int*)d_in[1];
    const int*   utseq = (const int*)d_in[2];
    const int*   cseq  = (const int*)d_in[3];
    const float* h0    = (const float*)d_in[4];
    const float* Eq    = (const float*)d_in[5];
    const float* Eut   = (const float*)d_in[6];
    const float* Eit   = (const float*)d_in[7];
    const float* W1    = (const float*)d_in[8];
    const float* b1    = (const float*)d_in[9];
    const float* W2    = (const float*)d_in[10];
    const float* b2    = (const float*)d_in[11];
    const float* W3    = (const float*)d_in[12];
    const float* b3    = (const float*)d_in[13];
    const float* W4    = (const float*)d_in[14];
    const float* b4    = (const float*)d_in[15];
    const float* Wa    = (const float*)d_in[16];
    const float* ba    = (const float*)d_in[17];
    const float* Wd    = (const float*)d_in[18];
    const float* bd    = (const float*)d_in[19];
    const float* Wdisc = (const float*)d_in[20];
    const float* bdisc = (const float*)d_in[21];
    float* pred = (float*)d_out;
    float* ws = (float*)d_ws;

    // --- choose time-chunk so scratch fits ws_size (constant per run -> graph-safe)
    const size_t fixedf = 65536 + 147456 + 384 + 128 + 131072 + 32768; // 377344 floats
    size_t ws_f = ws_size / 4;
    int T_CH = 4;
    {
        const int cands[8] = {511, 256, 128, 64, 32, 16, 8, 4};
        for (int ci = 0; ci < 8; ++ci) {
            size_t T = (size_t)cands[ci];
            size_t need = fixedf + (T + 2) * 32768 * 2 + T * 98304;
            if (need <= ws_f) { T_CH = cands[ci]; break; }
        }
    }

    // ws layout (floats)
    float* Wld     = ws;                          // 65536
    float* Wz      = Wld + 65536;                 // 147456
    float* bz      = Wz + 147456;                 // 384
    float* w1csum  = bz + 384;                    // 128
    float* discb   = w1csum + 128;                // 131072
    float* hcarry  = discb + 131072;              // 32768
    float* learn_c = hcarry + 32768;              // (T_CH+2)*32768
    float* diff_c  = learn_c + (size_t)(T_CH + 2) * 32768;
    float* U_c     = diff_c + (size_t)(T_CH + 2) * 32768;  // T_CH*98304

    k_pack<<<256, 256, 0, stream>>>(W1, Wd, W2, W3, W4, b2, b3, b4, h0,
                                    Wld, Wz, bz, w1csum, hcarry, pred);
    k_disc<<<2048, 256, 0, stream>>>(qseq, Eq, Wdisc, bdisc, discb);

    for (int t0 = 0; t0 < S_LEN - 1; t0 += T_CH) {
        int T_len = S_LEN - 1 - t0; if (T_len > T_CH) T_len = T_CH;
        int s_lo = (t0 == 0) ? 0 : (t0 - 1);
        int s_hi = t0 + T_len + 1;                 // exclusive; <= 512
        int out_row0 = (s_lo - (t0 - 1)) * 256;    // 256 for first chunk, else 0
        k_ld_gemm<<<dim3((s_hi - s_lo) * 4, 2), 256, 0, stream>>>(
            qseq, utseq, cseq, Eq, Eut, Wld, b1, bd, w1csum,
            learn_c, diff_c, s_lo, out_row0);
        k_u_gemm<<<dim3(T_len * 4, 3), 256, 0, stream>>>(
            itseq, Eit, learn_c, Wz, bz, U_c, t0);
        k_scan<<<256, 512, 0, stream>>>(
            U_c, diff_c, discb, hcarry, W2, W3, W4, Wa, ba, pred, t0, T_len);
    }
}

// Round 3
// 916.979 us; speedup vs baseline: 1.9617x; 1.9617x over previous
//
#include <hip/hip_runtime.h>
#include <math.h>

#define S_LEN 512
#define B_SZ  256

typedef _Float16 f16x8 __attribute__((ext_vector_type(8)));
typedef float    f32x4 __attribute__((ext_vector_type(4)));

__device__ __forceinline__ float sigm(float x) { return 1.0f / (1.0f + __expf(-x)); }

// LDS tile byte offset with G4 XOR swizzle: row-major [128 rows][128 B], conflict-min.
__device__ __forceinline__ int swz(int row, int byte_in_row) {
    return row * 128 + (byte_in_row ^ ((row & 7) << 4));
}

// padded quarter layout for scan vectors: quarter q (32 floats) at offset q*40
#define PQ(k) ((((k) >> 5) * 40) + ((k) & 31))

// ---------------- pack: fp16 tables + packed fp16 weights + biases + h0/pred init --
__global__ void k_pack16(const float* __restrict__ W1, const float* __restrict__ Wd,
                         const float* __restrict__ W2, const float* __restrict__ W3,
                         const float* __restrict__ W4, const float* __restrict__ b2,
                         const float* __restrict__ b3, const float* __restrict__ b4,
                         const float* __restrict__ h0,
                         const float* __restrict__ Eq, const float* __restrict__ Eut,
                         const float* __restrict__ Eit,
                         _Float16* __restrict__ Eq16, _Float16* __restrict__ Eut16,
                         _Float16* __restrict__ Eit16,
                         _Float16* __restrict__ Wld16, _Float16* __restrict__ Wz16,
                         float* __restrict__ bz, float* __restrict__ w1csum,
                         float* __restrict__ hcarry, float* __restrict__ pred)
{
    int idx0 = blockIdx.x * blockDim.x + threadIdx.x;
    int stride = gridDim.x * blockDim.x;
    for (int i = idx0; i < 10001 * 128; i += stride) Eq16[i] = (_Float16)Eq[i];
    for (int i = idx0; i < 1025 * 128; i += stride) Eut16[i] = (_Float16)Eut[i];
    for (int i = idx0; i < 1025 * 128; i += stride) Eit16[i] = (_Float16)Eit[i];
    // Wld16 [256 out][256 in]: rows 0..127 -> W1[:,0:256]; rows 128..255 -> [Wd | 0]
    for (int idx = idx0; idx < 256 * 256; idx += stride) {
        int c = idx >> 8, j = idx & 255;
        float v;
        if (c < 128) v = W1[c * 306 + j];
        else         v = (j < 128) ? Wd[(c - 128) * 128 + j] : 0.f;
        Wld16[idx] = (_Float16)v;
    }
    // Wz16 [384 out][384 in]: A = [lp(0:128) | it(128:256) | le(256:384)]
    for (int idx = idx0; idx < 384 * 384; idx += stride) {
        int c = idx / 384, j = idx - c * 384;
        float v;
        if (c < 128)      v = W2[c * 512 + j];
        else if (c < 256) v = W3[(c - 128) * 512 + j];
        else              v = (j >= 128 && j < 256) ? W4[(c - 256) * 384 + 128 + j] : 0.f;
        Wz16[idx] = (_Float16)v;
    }
    for (int idx = idx0; idx < 384; idx += stride)
        bz[idx] = (idx < 128) ? b2[idx] : (idx < 256 ? b3[idx - 128] : b4[idx - 256]);
    for (int idx = idx0; idx < 128; idx += stride) {
        float s = 0.f;
        for (int j = 0; j < 50; ++j) s += W1[idx * 306 + 256 + j];
        w1csum[idx] = s;
    }
    for (int idx = idx0; idx < 256 * 128; idx += stride) hcarry[idx] = h0[idx];
    for (int idx = idx0; idx < 256; idx += stride) pred[(size_t)idx * S_LEN] = 0.f;
}

// ---------------- disc: sigmoid(q . Wdisc + bdisc) * 10 (f32, full sequence) ------
__global__ __launch_bounds__(256) void k_disc(const int* __restrict__ qseq,
                                              const float* __restrict__ Eq,
                                              const float* __restrict__ Wdisc,
                                              const float* __restrict__ bdisc,
                                              float* __restrict__ disc)
{
    __shared__ float wd[128];
    __shared__ float bds;
    if (threadIdx.x < 128) wd[threadIdx.x] = Wdisc[threadIdx.x];
    if (threadIdx.x == 0) bds = bdisc[0];
    __syncthreads();
    int r = blockIdx.x * 64 + (threadIdx.x >> 2);
    int q4 = threadIdx.x & 3;
    const float* qe = Eq + (size_t)qseq[r] * 128 + q4 * 32;
    float s = 0.f;
#pragma unroll
    for (int j = 0; j < 32; ++j) s = fmaf(qe[j], wd[q4 * 32 + j], s);
    s += __shfl_xor(s, 1, 64);
    s += __shfl_xor(s, 2, 64);
    if (q4 == 0) disc[r] = sigm(s + bds) * 10.0f;
}

// ---------------- MFMA GEMM 1: learn (cb=0) / diff (cb=1); M=(s_hi-s_lo)*256, K=256
__global__ __launch_bounds__(256) void k_mm_ld(
    const int* __restrict__ qseq, const int* __restrict__ utseq, const int* __restrict__ cseq,
    const _Float16* __restrict__ Eq16, const _Float16* __restrict__ Eut16,
    const _Float16* __restrict__ Wld16, const float* __restrict__ b1,
    const float* __restrict__ bd, const float* __restrict__ w1csum,
    _Float16* __restrict__ learn16, _Float16* __restrict__ diff16,
    int s_lo, int out_row0)
{
    __shared__ _Float16 As[128 * 64];
    __shared__ _Float16 Bs[128 * 64];
    __shared__ int   ridxq[128];
    __shared__ int   ridxut[128];
    __shared__ float rcorr[128];
    __shared__ float cS[128];
    __shared__ float c2S[128];

    const int tid = threadIdx.x;
    const int vr0 = blockIdx.x * 128;
    const int cb = blockIdx.y;

    if (tid < 128) {
        int vr = vr0 + tid;
        int b = vr & 255, s = s_lo + (vr >> 8);
        int rin = b * S_LEN + s;
        ridxq[tid] = qseq[rin];
        ridxut[tid] = utseq[rin];
        rcorr[tid] = (float)cseq[rin];
        cS[tid] = (cb == 0) ? w1csum[tid] : 0.f;
        c2S[tid] = (cb == 0) ? b1[tid] : bd[tid];
    }
    __syncthreads();

    const int wid = tid >> 6, lane = tid & 63;
    const int wr = wid >> 1, wc = wid & 1;
    const int lrow = lane & 15, lkg = lane >> 4;
    const int arow = tid >> 1, apart = tid & 1;

    f32x4 acc[4][4];
#pragma unroll
    for (int i = 0; i < 4; ++i)
#pragma unroll
        for (int j = 0; j < 4; ++j) acc[i][j] = (f32x4){0.f, 0.f, 0.f, 0.f};

    for (int kb = 0; kb < 4; ++kb) {
        int k0 = kb * 64;
        const _Float16* srcA = (k0 < 128)
            ? (Eq16 + (size_t)ridxq[arow] * 128 + k0 + apart * 32)
            : (Eut16 + (size_t)ridxut[arow] * 128 + (k0 - 128) + apart * 32);
        const _Float16* srcB = Wld16 + (size_t)(cb * 128 + arow) * 256 + k0 + apart * 32;
#pragma unroll
        for (int j = 0; j < 4; ++j) {
            float4 va = *(const float4*)(srcA + j * 8);
            float4 vb = *(const float4*)(srcB + j * 8);
            int boff = apart * 64 + j * 16;
            *(float4*)((char*)As + swz(arow, boff)) = va;
            *(float4*)((char*)Bs + swz(arow, boff)) = vb;
        }
        __syncthreads();
#pragma unroll
        for (int ks = 0; ks < 2; ++ks) {
            f16x8 af[4], bf[4];
#pragma unroll
            for (int f = 0; f < 4; ++f) {
                int ar = wr * 64 + f * 16 + lrow;
                af[f] = *(const f16x8*)((const char*)As + swz(ar, ks * 64 + lkg * 16));
                int br = wc * 64 + f * 16 + lrow;
                bf[f] = *(const f16x8*)((const char*)Bs + swz(br, ks * 64 + lkg * 16));
            }
#pragma unroll
            for (int fi = 0; fi < 4; ++fi)
#pragma unroll
                for (int fj = 0; fj < 4; ++fj)
                    acc[fi][fj] = __builtin_amdgcn_mfma_f32_16x16x32_f16(
                        af[fi], bf[fj], acc[fi][fj], 0, 0, 0);
        }
        __syncthreads();
    }

    // epilogue
    if (cb == 0) {
#pragma unroll
        for (int fi = 0; fi < 4; ++fi) {
#pragma unroll
            for (int r = 0; r < 4; ++r) {
                int lr_ = wr * 64 + fi * 16 + (lane >> 4) * 4 + r;
                int grow = vr0 + out_row0 + lr_;
                float corr = rcorr[lr_];
#pragma unroll
                for (int fj = 0; fj < 4; ++fj) {
                    int col = wc * 64 + fj * 16 + (lane & 15);
                    float v = acc[fi][fj][r] + corr * cS[col] + c2S[col];
                    learn16[(size_t)grow * 128 + col] = (_Float16)v;
                }
            }
        }
    } else {
#pragma unroll
        for (int fi = 0; fi < 4; ++fi) {
#pragma unroll
            for (int r = 0; r < 4; ++r) {
                int lr_ = wr * 64 + fi * 16 + (lane >> 4) * 4 + r;
                int grow = vr0 + out_row0 + lr_;
#pragma unroll
                for (int fj = 0; fj < 4; ++fj) {
                    int col = wc * 64 + fj * 16 + (lane & 15);
                    float v = sigm(acc[fi][fj][r] + c2S[col]);
                    diff16[(size_t)grow * 128 + col] = (_Float16)v;
                }
            }
        }
    }
}

// ---------------- MFMA GEMM 2: U16[ur, cb*128..] , M=T_len*256, K=384 -------------
__global__ __launch_bounds__(256) void k_mm_u(
    const int* __restrict__ itseq, const _Float16* __restrict__ Eit16,
    const _Float16* __restrict__ learn16, const _Float16* __restrict__ Wz16,
    const float* __restrict__ bz, _Float16* __restrict__ U16, int t0)
{
    __shared__ _Float16 As[128 * 64];
    __shared__ _Float16 Bs[128 * 64];
    __shared__ int   itidx[128];
    __shared__ float bzS[128];

    const int tid = threadIdx.x;
    const int ur0 = blockIdx.x * 128;
    const int cb = blockIdx.y;
    const int t = t0 + (ur0 >> 8);
    const bool tzero = (t == 0);

    if (tid < 128) {
        int b = (ur0 + tid) & 255;
        itidx[tid] = itseq[b * S_LEN + t];
        bzS[tid] = bz[cb * 128 + tid];
    }
    __syncthreads();

    const int wid = tid >> 6, lane = tid & 63;
    const int wr = wid >> 1, wc = wid & 1;
    const int lrow = lane & 15, lkg = lane >> 4;
    const int arow = tid >> 1, apart = tid & 1;

    f32x4 acc[4][4];
#pragma unroll
    for (int i = 0; i < 4; ++i)
#pragma unroll
        for (int j = 0; j < 4; ++j) acc[i][j] = (f32x4){0.f, 0.f, 0.f, 0.f};

    for (int kb = 0; kb < 6; ++kb) {
        int k0 = kb * 64;
        int sec = k0 >> 7;
        int off = (k0 & 127) + apart * 32;
        const _Float16* srcA;
        if (sec == 0)      srcA = tzero ? nullptr : (learn16 + (size_t)(ur0 + arow) * 128 + off);
        else if (sec == 1) srcA = Eit16 + (size_t)itidx[arow] * 128 + off;
        else               srcA = learn16 + (size_t)(ur0 + arow + 256) * 128 + off;
        const _Float16* srcB = Wz16 + (size_t)(cb * 128 + arow) * 384 + k0 + apart * 32;
#pragma unroll
        for (int j = 0; j < 4; ++j) {
            float4 va;
            if (srcA) va = *(const float4*)(srcA + j * 8);
            else { va.x = va.y = va.z = va.w = 0.f; }
            float4 vb = *(const float4*)(srcB + j * 8);
            int boff = apart * 64 + j * 16;
            *(float4*)((char*)As + swz(arow, boff)) = va;
            *(float4*)((char*)Bs + swz(arow, boff)) = vb;
        }
        __syncthreads();
#pragma unroll
        for (int ks = 0; ks < 2; ++ks) {
            f16x8 af[4], bf[4];
#pragma unroll
            for (int f = 0; f < 4; ++f) {
                int ar = wr * 64 + f * 16 + lrow;
                af[f] = *(const f16x8*)((const char*)As + swz(ar, ks * 64 + lkg * 16));
                int br = wc * 64 + f * 16 + lrow;
                bf[f] = *(const f16x8*)((const char*)Bs + swz(br, ks * 64 + lkg * 16));
            }
#pragma unroll
            for (int fi = 0; fi < 4; ++fi)
#pragma unroll
                for (int fj = 0; fj < 4; ++fj)
                    acc[fi][fj] = __builtin_amdgcn_mfma_f32_16x16x32_f16(
                        af[fi], bf[fj], acc[fi][fj], 0, 0, 0);
        }
        __syncthreads();
    }

#pragma unroll
    for (int fi = 0; fi < 4; ++fi) {
#pragma unroll
        for (int r = 0; r < 4; ++r) {
            int lr_ = wr * 64 + fi * 16 + (lane >> 4) * 4 + r;
            int grow = ur0 + lr_;
#pragma unroll
            for (int fj = 0; fj < 4; ++fj) {
                int col = wc * 64 + fj * 16 + (lane & 15);
                float v = acc[fi][fj][r] + bzS[col];
                U16[(size_t)grow * 384 + cb * 128 + col] = (_Float16)v;
            }
        }
    }
}

// ---------------- scan (chunked): padded LDS quarters, fp16 U/diff ---------------
__global__ __launch_bounds__(512) void k_scan(
    const _Float16* __restrict__ U16, const _Float16* __restrict__ diff16,
    const float* __restrict__ disc, float* __restrict__ hcarry,
    const float* __restrict__ W2, const float* __restrict__ W3,
    const float* __restrict__ W4, const float* __restrict__ Wa,
    const float* __restrict__ ba, float* __restrict__ pred,
    int t0, int T_len)
{
    const int b = blockIdx.x;
    const int tid = threadIdx.x;
    const int k = tid >> 2;          // output element 0..127
    const int q = tid & 3;           // j-quarter
    const int j0p = q * 40;          // padded quarter base

    float w2h[32], w3h[32], w4h[32], w4l[32], wak[32];
    {
        const float* p2 = W2 + k * 512 + 384 + q * 32;
        const float* p3 = W3 + k * 512 + 384 + q * 32;
        const float* p4h = W4 + k * 384 + q * 32;
        const float* p4l = W4 + k * 384 + 128 + q * 32;
        const float* pa = Wa + k * 128 + q * 32;
#pragma unroll
        for (int jj = 0; jj < 32; ++jj) {
            w2h[jj] = p2[jj]; w3h[jj] = p3[jj]; w4h[jj] = p4h[jj];
            w4l[jj] = p4l[jj]; wak[jj] = pa[jj];
        }
    }
    const float bak = ba[k];

    __shared__ __align__(16) float hbuf[2][160];
    __shared__ __align__(16) float LGs[160];
    __shared__ __align__(16) float term[128];

    if (tid < 128) hbuf[0][PQ(tid)] = hcarry[b * 128 + tid];
    __syncthreads();

    const float* grow_ = disc + (size_t)b * S_LEN;

    for (int lt = 0; lt < T_len; ++lt) {
        const int cur = lt & 1;
        const float* hp = hbuf[cur];
        const _Float16* Ut = U16 + ((size_t)lt * B_SZ + b) * 384;
        float u2 = (float)Ut[k];
        float u3 = (float)Ut[128 + k];
        float u4 = (float)Ut[256 + k];
        float dk = (float)diff16[((size_t)(lt + 2) * B_SZ + b) * 128 + k];
        float g = grow_[t0 + lt + 1];

        // ---- stage 1: s2,s3,s4 = h_pre . {W2h,W3h,W4h}[k, quarter]
        float hr[32];
#pragma unroll
        for (int i = 0; i < 8; ++i) {
            float4 v = *(const float4*)&hp[j0p + i * 4];
            hr[i * 4 + 0] = v.x; hr[i * 4 + 1] = v.y; hr[i * 4 + 2] = v.z; hr[i * 4 + 3] = v.w;
        }
        float s2 = 0.f, s3 = 0.f, s4 = 0.f;
#pragma unroll
        for (int jj = 0; jj < 32; ++jj) {
            s2 = fmaf(hr[jj], w2h[jj], s2);
            s3 = fmaf(hr[jj], w3h[jj], s3);
            s4 = fmaf(hr[jj], w4h[jj], s4);
        }
        s2 += __shfl_xor(s2, 1, 64); s2 += __shfl_xor(s2, 2, 64);
        s3 += __shfl_xor(s3, 1, 64); s3 += __shfl_xor(s3, 2, 64);
        s4 += __shfl_xor(s4, 1, 64); s4 += __shfl_xor(s4, 2, 64);
        if (q == 0) {
            float gain = 2.f * sigm(2.f * (s2 + u2)) - 1.f;   // tanh
            float gl = sigm(s3 + u3);
            LGs[PQ(k)] = gl * (gain + 1.f) * 0.5f;
        }
        __syncthreads();

        // ---- stage 2: gamma_f, h_new
        float lr[32];
#pragma unroll
        for (int i = 0; i < 8; ++i) {
            float4 v = *(const float4*)&LGs[j0p + i * 4];
            lr[i * 4 + 0] = v.x; lr[i * 4 + 1] = v.y; lr[i * 4 + 2] = v.z; lr[i * 4 + 3] = v.w;
        }
        float s4l = 0.f;
#pragma unroll
        for (int jj = 0; jj < 32; ++jj) s4l = fmaf(lr[jj], w4l[jj], s4l);
        s4l += __shfl_xor(s4l, 1, 64); s4l += __shfl_xor(s4l, 2, 64);
        if (q == 0) {
            float gf = sigm(s4 + s4l + u4);
            hbuf[cur ^ 1][PQ(k)] = LGs[PQ(k)] + gf * hp[PQ(k)];
        }
        __syncthreads();

        // ---- stage 3: ability + per-channel term
        float hr2[32];
#pragma unroll
        for (int i = 0; i < 8; ++i) {
            float4 v = *(const float4*)&hbuf[cur ^ 1][j0p + i * 4];
            hr2[i * 4 + 0] = v.x; hr2[i * 4 + 1] = v.y; hr2[i * 4 + 2] = v.z; hr2[i * 4 + 3] = v.w;
        }
        float sa = 0.f;
#pragma unroll
        for (int jj = 0; jj < 32; ++jj) sa = fmaf(hr2[jj], wak[jj], sa);
        sa += __shfl_xor(sa, 1, 64); sa += __shfl_xor(sa, 2, 64);
        if (q == 0) {
            float ab = sigm(sa + bak);
            term[k] = (ab - dk) * dk;
        }
        __syncthreads();

        // ---- y reduction (wave 0)
        if (tid < 64) {
            float v = term[tid] + term[tid + 64];
            v += __shfl_xor(v, 32, 64);
            v += __shfl_xor(v, 16, 64);
            v += __shfl_xor(v, 8, 64);
            v += __shfl_xor(v, 4, 64);
            v += __shfl_xor(v, 2, 64);
            v += __shfl_xor(v, 1, 64);
            if (tid == 0) pred[(size_t)b * S_LEN + t0 + lt + 1] = sigm(g * v);
        }
    }
    __syncthreads();
    if (tid < 128) hcarry[b * 128 + tid] = hbuf[T_len & 1][PQ(tid)];
}

extern "C" void kernel_launch(void* const* d_in, const int* in_sizes, int n_in,
                              void* d_out, int out_size, void* d_ws, size_t ws_size,
                              hipStream_t stream)
{
    const int*   qseq  = (const int*)d_in[0];
    const int*   itseq = (const int*)d_in[1];
    const int*   utseq = (const int*)d_in[2];
    const int*   cseq  = (const int*)d_in[3];
    const float* h0    = (const float*)d_in[4];
    const float* Eq    = (const float*)d_in[5];
    const float* Eut   = (const float*)d_in[6];
    const float* Eit   = (const float*)d_in[7];
    const float* W1    = (const float*)d_in[8];
    const float* b1    = (const float*)d_in[9];
    const float* W2    = (const float*)d_in[10];
    const float* b2    = (const float*)d_in[11];
    const float* W3    = (const float*)d_in[12];
    const float* b3    = (const float*)d_in[13];
    const float* W4    = (const float*)d_in[14];
    const float* b4    = (const float*)d_in[15];
    const float* Wa    = (const float*)d_in[16];
    const float* ba    = (const float*)d_in[17];
    const float* Wd    = (const float*)d_in[18];
    const float* bd    = (const float*)d_in[19];
    const float* Wdisc = (const float*)d_in[20];
    const float* bdisc = (const float*)d_in[21];
    float* pred = (float*)d_out;

    // --- fixed-region layout (bytes, all 256B-multiples) ---
    char* p = (char*)d_ws;
    float* bz      = (float*)p;           p += 384 * 4;
    float* w1csum  = (float*)p;           p += 128 * 4;
    float* discb   = (float*)p;           p += 131072 * 4;
    float* hcarry  = (float*)p;           p += 32768 * 4;
    _Float16* Eq16  = (_Float16*)p;       p += 10001 * 128 * 2;
    _Float16* Eut16 = (_Float16*)p;       p += 1025 * 128 * 2;
    _Float16* Eit16 = (_Float16*)p;       p += 1025 * 128 * 2;
    _Float16* Wld16 = (_Float16*)p;       p += 256 * 256 * 2;
    _Float16* Wz16  = (_Float16*)p;       p += 384 * 384 * 2;
    const size_t fixed_bytes = (size_t)(p - (char*)d_ws);   // ~4.17 MB

    // --- choose time-chunk so fp16 scratch fits ws_size ---
    int T_CH = 4;
    {
        const int cands[8] = {511, 256, 128, 64, 32, 16, 8, 4};
        for (int ci = 0; ci < 8; ++ci) {
            size_t T = (size_t)cands[ci];
            size_t need = fixed_bytes + (T + 2) * 131072 + T * 196608;
            if (need <= ws_size) { T_CH = cands[ci]; break; }
        }
    }
    _Float16* learn16 = (_Float16*)p;     p += (size_t)(T_CH + 2) * 65536 * 2;
    _Float16* diff16  = (_Float16*)p;     p += (size_t)(T_CH + 2) * 65536 * 2;
    _Float16* U16     = (_Float16*)p;

    k_pack16<<<2048, 256, 0, stream>>>(W1, Wd, W2, W3, W4, b2, b3, b4, h0,
                                       Eq, Eut, Eit, Eq16, Eut16, Eit16,
                                       Wld16, Wz16, bz, w1csum, hcarry, pred);
    k_disc<<<2048, 256, 0, stream>>>(qseq, Eq, Wdisc, bdisc, discb);

    for (int t0 = 0; t0 < S_LEN - 1; t0 += T_CH) {
        int T_len = S_LEN - 1 - t0; if (T_len > T_CH) T_len = T_CH;
        int s_lo = (t0 == 0) ? 0 : (t0 - 1);
        int s_hi = t0 + T_len + 1;                 // exclusive; <= 512
        int out_row0 = (s_lo - (t0 - 1)) * 256;    // 256 for first chunk, else 0
        k_mm_ld<<<dim3((s_hi - s_lo) * 2, 2), 256, 0, stream>>>(
            qseq, utseq, cseq, Eq16, Eut16, Wld16, b1, bd, w1csum,
            learn16, diff16, s_lo, out_row0);
        k_mm_u<<<dim3(T_len * 2, 3), 256, 0, stream>>>(
            itseq, Eit16, learn16, Wz16, bz, U16, t0);
        k_scan<<<256, 512, 0, stream>>>(
            U16, diff16, discb, hcarry, W2, W3, W4, Wa, ba, pred, t0, T_len);
    }
}

// Round 4
// 854.401 us; speedup vs baseline: 2.1054x; 1.0732x over previous
//
#include <hip/hip_runtime.h>
#include <math.h>

#define S_LEN 512
#define B_SZ  256

typedef _Float16 f16x8 __attribute__((ext_vector_type(8)));
typedef _Float16 h2    __attribute__((ext_vector_type(2)));
typedef float    f32x4 __attribute__((ext_vector_type(4)));

__device__ __forceinline__ float sigm(float x) { return 1.0f / (1.0f + __expf(-x)); }

__device__ __forceinline__ float fdot2(h2 a, h2 b, float c) {
#if __has_builtin(__builtin_amdgcn_fdot2)
    return __builtin_amdgcn_fdot2(a, b, c, false);
#else
    return c + (float)a.x * (float)b.x + (float)a.y * (float)b.y;
#endif
}

// LDS tile byte offset with G4 XOR swizzle: row-major [128 rows][128 B]
__device__ __forceinline__ int swz(int row, int byte_in_row) {
    return row * 128 + (byte_in_row ^ ((row & 7) << 4));
}

// ---------------- pack: fp16 tables + packed fp16 weights + biases + h0/pred init --
__global__ void k_pack16(const float* __restrict__ W1, const float* __restrict__ Wd,
                         const float* __restrict__ W2, const float* __restrict__ W3,
                         const float* __restrict__ W4, const float* __restrict__ b2,
                         const float* __restrict__ b3, const float* __restrict__ b4,
                         const float* __restrict__ h0, const float* __restrict__ Wa,
                         const float* __restrict__ Eq, const float* __restrict__ Eut,
                         const float* __restrict__ Eit,
                         _Float16* __restrict__ Eq16, _Float16* __restrict__ Eut16,
                         _Float16* __restrict__ Eit16,
                         _Float16* __restrict__ Wld16, _Float16* __restrict__ Wz16,
                         h2* __restrict__ Wa16p,
                         float* __restrict__ bz, float* __restrict__ w1csum,
                         float* __restrict__ hcarry, float* __restrict__ pred)
{
    int idx0 = blockIdx.x * blockDim.x + threadIdx.x;
    int stride = gridDim.x * blockDim.x;
    for (int i = idx0; i < 10001 * 128; i += stride) Eq16[i] = (_Float16)Eq[i];
    for (int i = idx0; i < 1025 * 128; i += stride) Eut16[i] = (_Float16)Eut[i];
    for (int i = idx0; i < 1025 * 128; i += stride) Eit16[i] = (_Float16)Eit[i];
    for (int idx = idx0; idx < 256 * 256; idx += stride) {
        int c = idx >> 8, j = idx & 255;
        float v;
        if (c < 128) v = W1[c * 306 + j];
        else         v = (j < 128) ? Wd[(c - 128) * 128 + j] : 0.f;
        Wld16[idx] = (_Float16)v;
    }
    for (int idx = idx0; idx < 384 * 384; idx += stride) {
        int c = idx / 384, j = idx - c * 384;
        float v;
        if (c < 128)      v = W2[c * 512 + j];
        else if (c < 256) v = W3[(c - 128) * 512 + j];
        else              v = (j >= 128 && j < 256) ? W4[(c - 256) * 384 + 128 + j] : 0.f;
        Wz16[idx] = (_Float16)v;
    }
    // Wa packed half2: [c][j] j=0..63
    for (int idx = idx0; idx < 128 * 64; idx += stride) {
        int c = idx >> 6, j = idx & 63;
        h2 v; v.x = (_Float16)Wa[c * 128 + 2 * j]; v.y = (_Float16)Wa[c * 128 + 2 * j + 1];
        Wa16p[idx] = v;
    }
    for (int idx = idx0; idx < 384; idx += stride)
        bz[idx] = (idx < 128) ? b2[idx] : (idx < 256 ? b3[idx - 128] : b4[idx - 256]);
    for (int idx = idx0; idx < 128; idx += stride) {
        float s = 0.f;
        for (int j = 0; j < 50; ++j) s += W1[idx * 306 + 256 + j];
        w1csum[idx] = s;
    }
    for (int idx = idx0; idx < 256 * 128; idx += stride) hcarry[idx] = h0[idx];
    for (int idx = idx0; idx < 256; idx += stride) pred[(size_t)idx * S_LEN] = 0.f;
}

// ---------------- disc: sigmoid(q . Wdisc + bdisc) * 10 (f32, full sequence) ------
__global__ __launch_bounds__(256) void k_disc(const int* __restrict__ qseq,
                                              const float* __restrict__ Eq,
                                              const float* __restrict__ Wdisc,
                                              const float* __restrict__ bdisc,
                                              float* __restrict__ disc)
{
    __shared__ float wd[128];
    __shared__ float bds;
    if (threadIdx.x < 128) wd[threadIdx.x] = Wdisc[threadIdx.x];
    if (threadIdx.x == 0) bds = bdisc[0];
    __syncthreads();
    int r = blockIdx.x * 64 + (threadIdx.x >> 2);
    int q4 = threadIdx.x & 3;
    const float* qe = Eq + (size_t)qseq[r] * 128 + q4 * 32;
    float s = 0.f;
#pragma unroll
    for (int j = 0; j < 32; ++j) s = fmaf(qe[j], wd[q4 * 32 + j], s);
    s += __shfl_xor(s, 1, 64);
    s += __shfl_xor(s, 2, 64);
    if (q4 == 0) disc[r] = sigm(s + bds) * 10.0f;
}

// ---------------- MFMA GEMM 1: learn (cb=0) / diff (cb=1); K=256 ------------------
__global__ __launch_bounds__(256) void k_mm_ld(
    const int* __restrict__ qseq, const int* __restrict__ utseq, const int* __restrict__ cseq,
    const _Float16* __restrict__ Eq16, const _Float16* __restrict__ Eut16,
    const _Float16* __restrict__ Wld16, const float* __restrict__ b1,
    const float* __restrict__ bd, const float* __restrict__ w1csum,
    _Float16* __restrict__ learn16, _Float16* __restrict__ diff16,
    int s_lo, int out_row0)
{
    __shared__ _Float16 As[128 * 64];
    __shared__ _Float16 Bs[128 * 64];
    __shared__ int   ridxq[128];
    __shared__ int   ridxut[128];
    __shared__ float rcorr[128];
    __shared__ float cS[128];
    __shared__ float c2S[128];

    const int tid = threadIdx.x;
    const int vr0 = blockIdx.x * 128;
    const int cb = blockIdx.y;

    if (tid < 128) {
        int vr = vr0 + tid;
        int b = vr & 255, s = s_lo + (vr >> 8);
        int rin = b * S_LEN + s;
        ridxq[tid] = qseq[rin];
        ridxut[tid] = utseq[rin];
        rcorr[tid] = (float)cseq[rin];
        cS[tid] = (cb == 0) ? w1csum[tid] : 0.f;
        c2S[tid] = (cb == 0) ? b1[tid] : bd[tid];
    }
    __syncthreads();

    const int wid = tid >> 6, lane = tid & 63;
    const int wr = wid >> 1, wc = wid & 1;
    const int lrow = lane & 15, lkg = lane >> 4;
    const int arow = tid >> 1, apart = tid & 1;

    f32x4 acc[4][4];
#pragma unroll
    for (int i = 0; i < 4; ++i)
#pragma unroll
        for (int j = 0; j < 4; ++j) acc[i][j] = (f32x4){0.f, 0.f, 0.f, 0.f};

    for (int kb = 0; kb < 4; ++kb) {
        int k0 = kb * 64;
        const _Float16* srcA = (k0 < 128)
            ? (Eq16 + (size_t)ridxq[arow] * 128 + k0 + apart * 32)
            : (Eut16 + (size_t)ridxut[arow] * 128 + (k0 - 128) + apart * 32);
        const _Float16* srcB = Wld16 + (size_t)(cb * 128 + arow) * 256 + k0 + apart * 32;
#pragma unroll
        for (int j = 0; j < 4; ++j) {
            float4 va = *(const float4*)(srcA + j * 8);
            float4 vb = *(const float4*)(srcB + j * 8);
            int boff = apart * 64 + j * 16;
            *(float4*)((char*)As + swz(arow, boff)) = va;
            *(float4*)((char*)Bs + swz(arow, boff)) = vb;
        }
        __syncthreads();
#pragma unroll
        for (int ks = 0; ks < 2; ++ks) {
            f16x8 af[4], bf[4];
#pragma unroll
            for (int f = 0; f < 4; ++f) {
                int ar = wr * 64 + f * 16 + lrow;
                af[f] = *(const f16x8*)((const char*)As + swz(ar, ks * 64 + lkg * 16));
                int br = wc * 64 + f * 16 + lrow;
                bf[f] = *(const f16x8*)((const char*)Bs + swz(br, ks * 64 + lkg * 16));
            }
#pragma unroll
            for (int fi = 0; fi < 4; ++fi)
#pragma unroll
                for (int fj = 0; fj < 4; ++fj)
                    acc[fi][fj] = __builtin_amdgcn_mfma_f32_16x16x32_f16(
                        af[fi], bf[fj], acc[fi][fj], 0, 0, 0);
        }
        __syncthreads();
    }

    if (cb == 0) {
#pragma unroll
        for (int fi = 0; fi < 4; ++fi) {
#pragma unroll
            for (int r = 0; r < 4; ++r) {
                int lr_ = wr * 64 + fi * 16 + (lane >> 4) * 4 + r;
                int grow = vr0 + out_row0 + lr_;
                float corr = rcorr[lr_];
#pragma unroll
                for (int fj = 0; fj < 4; ++fj) {
                    int col = wc * 64 + fj * 16 + (lane & 15);
                    float v = acc[fi][fj][r] + corr * cS[col] + c2S[col];
                    learn16[(size_t)grow * 128 + col] = (_Float16)v;
                }
            }
        }
    } else {
#pragma unroll
        for (int fi = 0; fi < 4; ++fi) {
#pragma unroll
            for (int r = 0; r < 4; ++r) {
                int lr_ = wr * 64 + fi * 16 + (lane >> 4) * 4 + r;
                int grow = vr0 + out_row0 + lr_;
#pragma unroll
                for (int fj = 0; fj < 4; ++fj) {
                    int col = wc * 64 + fj * 16 + (lane & 15);
                    float v = sigm(acc[fi][fj][r] + c2S[col]);
                    diff16[(size_t)grow * 128 + col] = (_Float16)v;
                }
            }
        }
    }
}

// ---------------- MFMA GEMM 2: U16[ur, cb*128..] , K=384 --------------------------
__global__ __launch_bounds__(256) void k_mm_u(
    const int* __restrict__ itseq, const _Float16* __restrict__ Eit16,
    const _Float16* __restrict__ learn16, const _Float16* __restrict__ Wz16,
    const float* __restrict__ bz, _Float16* __restrict__ U16, int t0)
{
    __shared__ _Float16 As[128 * 64];
    __shared__ _Float16 Bs[128 * 64];
    __shared__ int   itidx[128];
    __shared__ float bzS[128];

    const int tid = threadIdx.x;
    const int ur0 = blockIdx.x * 128;
    const int cb = blockIdx.y;
    const int t = t0 + (ur0 >> 8);
    const bool tzero = (t == 0);

    if (tid < 128) {
        int b = (ur0 + tid) & 255;
        itidx[tid] = itseq[b * S_LEN + t];
        bzS[tid] = bz[cb * 128 + tid];
    }
    __syncthreads();

    const int wid = tid >> 6, lane = tid & 63;
    const int wr = wid >> 1, wc = wid & 1;
    const int lrow = lane & 15, lkg = lane >> 4;
    const int arow = tid >> 1, apart = tid & 1;

    f32x4 acc[4][4];
#pragma unroll
    for (int i = 0; i < 4; ++i)
#pragma unroll
        for (int j = 0; j < 4; ++j) acc[i][j] = (f32x4){0.f, 0.f, 0.f, 0.f};

    for (int kb = 0; kb < 6; ++kb) {
        int k0 = kb * 64;
        int sec = k0 >> 7;
        int off = (k0 & 127) + apart * 32;
        const _Float16* srcA;
        if (sec == 0)      srcA = tzero ? nullptr : (learn16 + (size_t)(ur0 + arow) * 128 + off);
        else if (sec == 1) srcA = Eit16 + (size_t)itidx[arow] * 128 + off;
        else               srcA = learn16 + (size_t)(ur0 + arow + 256) * 128 + off;
        const _Float16* srcB = Wz16 + (size_t)(cb * 128 + arow) * 384 + k0 + apart * 32;
#pragma unroll
        for (int j = 0; j < 4; ++j) {
            float4 va;
            if (srcA) va = *(const float4*)(srcA + j * 8);
            else { va.x = va.y = va.z = va.w = 0.f; }
            float4 vb = *(const float4*)(srcB + j * 8);
            int boff = apart * 64 + j * 16;
            *(float4*)((char*)As + swz(arow, boff)) = va;
            *(float4*)((char*)Bs + swz(arow, boff)) = vb;
        }
        __syncthreads();
#pragma unroll
        for (int ks = 0; ks < 2; ++ks) {
            f16x8 af[4], bf[4];
#pragma unroll
            for (int f = 0; f < 4; ++f) {
                int ar = wr * 64 + f * 16 + lrow;
                af[f] = *(const f16x8*)((const char*)As + swz(ar, ks * 64 + lkg * 16));
                int br = wc * 64 + f * 16 + lrow;
                bf[f] = *(const f16x8*)((const char*)Bs + swz(br, ks * 64 + lkg * 16));
            }
#pragma unroll
            for (int fi = 0; fi < 4; ++fi)
#pragma unroll
                for (int fj = 0; fj < 4; ++fj)
                    acc[fi][fj] = __builtin_amdgcn_mfma_f32_16x16x32_f16(
                        af[fi], bf[fj], acc[fi][fj], 0, 0, 0);
        }
        __syncthreads();
    }

#pragma unroll
    for (int fi = 0; fi < 4; ++fi) {
#pragma unroll
        for (int r = 0; r < 4; ++r) {
            int lr_ = wr * 64 + fi * 16 + (lane >> 4) * 4 + r;
            int grow = ur0 + lr_;
#pragma unroll
            for (int fj = 0; fj < 4; ++fj) {
                int col = wc * 64 + fj * 16 + (lane & 15);
                float v = acc[fi][fj][r] + bzS[col];
                U16[(size_t)grow * 384 + cb * 128 + col] = (_Float16)v;
            }
        }
    }
}

// ---------------- scan v3: 2 barriers/step, fdot2, u-prefetch, h16 stored to U16 --
__global__ __launch_bounds__(512) void k_scan(
    _Float16* __restrict__ U16, float* __restrict__ hcarry,
    const float* __restrict__ W2, const float* __restrict__ W3,
    const float* __restrict__ W4, int T_len)
{
    const int b = blockIdx.x;
    const int tid = threadIdx.x;
    const int k = tid >> 2;          // output channel 0..127
    const int q = tid & 3;           // j-quarter (32 elems = 16 pairs)

    // packed fp16 weight quarters in registers
    h2 w2h[16], w3h[16], w4h[16], w4l[16];
    {
        const float* p2 = W2 + k * 512 + 384 + q * 32;
        const float* p3 = W3 + k * 512 + 384 + q * 32;
        const float* p4h = W4 + k * 384 + q * 32;
        const float* p4l = W4 + k * 384 + 128 + q * 32;
#pragma unroll
        for (int j = 0; j < 16; ++j) {
            h2 a, c, d, e;
            a.x = (_Float16)p2[2 * j];  a.y = (_Float16)p2[2 * j + 1];
            c.x = (_Float16)p3[2 * j];  c.y = (_Float16)p3[2 * j + 1];
            d.x = (_Float16)p4h[2 * j]; d.y = (_Float16)p4h[2 * j + 1];
            e.x = (_Float16)p4l[2 * j]; e.y = (_Float16)p4l[2 * j + 1];
            w2h[j] = a; w3h[j] = c; w4h[j] = d; w4l[j] = e;
        }
    }

    __shared__ h2 hp16[64];     // packed fp16 h (128 halfs)
    __shared__ h2 lg16[64];     // packed fp16 LG

    float h_k = 0.f;            // f32 carried state (valid on q==0 lanes)
    if (q == 0) h_k = hcarry[b * 128 + k];
    if (tid < 64) {
        h2 v;
        v.x = (_Float16)hcarry[b * 128 + 2 * tid];
        v.y = (_Float16)hcarry[b * 128 + 2 * tid + 1];
        hp16[tid] = v;
    }
    __syncthreads();

    _Float16* Ub = U16 + (size_t)b * 384;
    // prefetch step 0
    float u2c = (float)Ub[k], u3c = (float)Ub[128 + k], u4c = (float)Ub[256 + k];

    for (int lt = 0; lt < T_len; ++lt) {
        // prefetch next step's u (hidden under this step's compute)
        float u2n = 0.f, u3n = 0.f, u4n = 0.f;
        if (lt + 1 < T_len) {
            const _Float16* Un = Ub + (size_t)(lt + 1) * (B_SZ * 384);
            u2n = (float)Un[k]; u3n = (float)Un[128 + k]; u4n = (float)Un[256 + k];
        }

        // ---- stage 1: s2,s3,s4 over h quarter
        h2 hrq[16];
        {
            const h2* hq = hp16 + q * 16;
#pragma unroll
            for (int j = 0; j < 16; ++j) hrq[j] = hq[j];
        }
        float s2 = 0.f, s3 = 0.f, s4 = 0.f;
#pragma unroll
        for (int j = 0; j < 16; ++j) {
            s2 = fdot2(hrq[j], w2h[j], s2);
            s3 = fdot2(hrq[j], w3h[j], s3);
            s4 = fdot2(hrq[j], w4h[j], s4);
        }
        s2 += __shfl_xor(s2, 1, 64); s2 += __shfl_xor(s2, 2, 64);
        s3 += __shfl_xor(s3, 1, 64); s3 += __shfl_xor(s3, 2, 64);
        s4 += __shfl_xor(s4, 1, 64); s4 += __shfl_xor(s4, 2, 64);
        float LG_k = 0.f;
        if (q == 0) {
            // LG = sigm(s3+u3) * sigm(2*(s2+u2))   [ = gl*(tanh+1)/2 ]
            LG_k = sigm(s3 + u3c) * sigm(2.f * (s2 + u2c));
            ((_Float16*)lg16)[k] = (_Float16)LG_k;
        }
        __syncthreads();

        // ---- stage 2: s4l over LG quarter; h update
        h2 lrq[16];
        {
            const h2* lq = lg16 + q * 16;
#pragma unroll
            for (int j = 0; j < 16; ++j) lrq[j] = lq[j];
        }
        float s4l = 0.f;
#pragma unroll
        for (int j = 0; j < 16; ++j) s4l = fdot2(lrq[j], w4l[j], s4l);
        s4l += __shfl_xor(s4l, 1, 64); s4l += __shfl_xor(s4l, 2, 64);
        if (q == 0) {
            float gf = sigm(s4 + s4l + u4c);
            h_k = LG_k + gf * h_k;
            ((_Float16*)hp16)[k] = (_Float16)h_k;
            // store h_t into U16 row lt (u2 slot already consumed)
            Ub[(size_t)lt * (B_SZ * 384) + k] = (_Float16)h_k;
        }
        __syncthreads();

        u2c = u2n; u3c = u3n; u4c = u4n;
    }
    if (q == 0) hcarry[b * 128 + k] = h_k;
}

// ---------------- post: ability + y for all (t,b) in chunk, parallel --------------
// rows r = lt*256 + b; h at U16[r*384 + 0..127]; diff at diff16[(r+512)*128 + c]
__global__ __launch_bounds__(256) void k_post(
    const _Float16* __restrict__ U16, const _Float16* __restrict__ diff16,
    const float* __restrict__ disc, const h2* __restrict__ Wa16p,
    const float* __restrict__ ba, float* __restrict__ pred, int t0)
{
    __shared__ h2 WaS[128 * 64];     // swizzled: [c][j ^ (c&31)]
    __shared__ uint hS[4][64];       // per-wave h row (packed pairs)

    const int tid = threadIdx.x;
    const int w = tid >> 6, lane = tid & 63;

    // stage Wa (swizzled word index to kill stride-256B bank conflicts)
    for (int idx = tid; idx < 128 * 64; idx += 256) {
        int c = idx >> 6, j = idx & 63;
        WaS[(c << 6) + (j ^ (c & 31))] = Wa16p[idx];
    }
    __syncthreads();

    const int c1 = lane, c2 = lane + 64;
    const float ba1 = ba[c1], ba2 = ba[c2];
    const int x1 = c1 & 31, x2 = c2 & 31;

    for (int it = 0; it < 8; ++it) {
        int r = blockIdx.x * 32 + w * 8 + it;
        int b = r & 255, t = t0 + (r >> 8);
        // stage h row
        const uint* hsrc = (const uint*)(U16 + (size_t)r * 384);
        hS[w][lane] = hsrc[lane];
        // prefetch d, g
        float d1 = (float)diff16[(size_t)(r + 512) * 128 + c1];
        float d2 = (float)diff16[(size_t)(r + 512) * 128 + c2];
        float g = disc[b * S_LEN + t + 1];
        __syncthreads();

        float dot1 = 0.f, dot2 = 0.f;
        const h2* hv = (const h2*)hS[w];
#pragma unroll
        for (int j = 0; j < 64; ++j) {
            h2 hj = hv[j];
            dot1 = fdot2(hj, WaS[(c1 << 6) + (j ^ x1)], dot1);
            dot2 = fdot2(hj, WaS[(c2 << 6) + (j ^ x2)], dot2);
        }
        float t1 = (sigm(dot1 + ba1) - d1) * d1;
        float t2 = (sigm(dot2 + ba2) - d2) * d2;
        float v = t1 + t2;
        v += __shfl_xor(v, 32, 64);
        v += __shfl_xor(v, 16, 64);
        v += __shfl_xor(v, 8, 64);
        v += __shfl_xor(v, 4, 64);
        v += __shfl_xor(v, 2, 64);
        v += __shfl_xor(v, 1, 64);
        if (lane == 0) pred[(size_t)b * S_LEN + t + 1] = sigm(g * v);
        __syncthreads();
    }
}

extern "C" void kernel_launch(void* const* d_in, const int* in_sizes, int n_in,
                              void* d_out, int out_size, void* d_ws, size_t ws_size,
                              hipStream_t stream)
{
    const int*   qseq  = (const int*)d_in[0];
    const int*   itseq = (const int*)d_in[1];
    const int*   utseq = (const int*)d_in[2];
    const int*   cseq  = (const int*)d_in[3];
    const float* h0    = (const float*)d_in[4];
    const float* Eq    = (const float*)d_in[5];
    const float* Eut   = (const float*)d_in[6];
    const float* Eit   = (const float*)d_in[7];
    const float* W1    = (const float*)d_in[8];
    const float* b1    = (const float*)d_in[9];
    const float* W2    = (const float*)d_in[10];
    const float* b2    = (const float*)d_in[11];
    const float* W3    = (const float*)d_in[12];
    const float* b3    = (const float*)d_in[13];
    const float* W4    = (const float*)d_in[14];
    const float* b4    = (const float*)d_in[15];
    const float* Wa    = (const float*)d_in[16];
    const float* ba    = (const float*)d_in[17];
    const float* Wd    = (const float*)d_in[18];
    const float* bd    = (const float*)d_in[19];
    const float* Wdisc = (const float*)d_in[20];
    const float* bdisc = (const float*)d_in[21];
    float* pred = (float*)d_out;

    // --- fixed-region layout ---
    char* p = (char*)d_ws;
    float* bz      = (float*)p;           p += 384 * 4;
    float* w1csum  = (float*)p;           p += 128 * 4;
    float* discb   = (float*)p;           p += 131072 * 4;
    float* hcarry  = (float*)p;           p += 32768 * 4;
    _Float16* Eq16  = (_Float16*)p;       p += 10001 * 128 * 2;
    _Float16* Eut16 = (_Float16*)p;       p += 1025 * 128 * 2;
    _Float16* Eit16 = (_Float16*)p;       p += 1025 * 128 * 2;
    _Float16* Wld16 = (_Float16*)p;       p += 256 * 256 * 2;
    _Float16* Wz16  = (_Float16*)p;       p += 384 * 384 * 2;
    h2*       Wa16p = (h2*)p;             p += 128 * 64 * 4;
    const size_t fixed_bytes = (size_t)(p - (char*)d_ws);

    int T_CH = 4;
    {
        const int cands[8] = {511, 256, 128, 64, 32, 16, 8, 4};
        for (int ci = 0; ci < 8; ++ci) {
            size_t T = (size_t)cands[ci];
            size_t need = fixed_bytes + (T + 2) * 131072 + T * 196608;
            if (need <= ws_size) { T_CH = cands[ci]; break; }
        }
    }
    _Float16* learn16 = (_Float16*)p;     p += (size_t)(T_CH + 2) * 65536 * 2;
    _Float16* diff16  = (_Float16*)p;     p += (size_t)(T_CH + 2) * 65536 * 2;
    _Float16* U16     = (_Float16*)p;

    k_pack16<<<2048, 256, 0, stream>>>(W1, Wd, W2, W3, W4, b2, b3, b4, h0, Wa,
                                       Eq, Eut, Eit, Eq16, Eut16, Eit16,
                                       Wld16, Wz16, Wa16p, bz, w1csum, hcarry, pred);
    k_disc<<<2048, 256, 0, stream>>>(qseq, Eq, Wdisc, bdisc, discb);

    for (int t0 = 0; t0 < S_LEN - 1; t0 += T_CH) {
        int T_len = S_LEN - 1 - t0; if (T_len > T_CH) T_len = T_CH;
        int s_lo = (t0 == 0) ? 0 : (t0 - 1);
        int s_hi = t0 + T_len + 1;
        int out_row0 = (s_lo - (t0 - 1)) * 256;
        k_mm_ld<<<dim3((s_hi - s_lo) * 2, 2), 256, 0, stream>>>(
            qseq, utseq, cseq, Eq16, Eut16, Wld16, b1, bd, w1csum,
            learn16, diff16, s_lo, out_row0);
        k_mm_u<<<dim3(T_len * 2, 3), 256, 0, stream>>>(
            itseq, Eit16, learn16, Wz16, bz, U16, t0);
        k_scan<<<256, 512, 0, stream>>>(U16, hcarry, W2, W3, W4, T_len);
        k_post<<<T_len * 8, 256, 0, stream>>>(U16, diff16, discb, Wa16p, ba, pred, t0);
    }
}

// Round 5
// 845.554 us; speedup vs baseline: 2.1274x; 1.0105x over previous
//
#include <hip/hip_runtime.h>
#include <math.h>

#define S_LEN 512
#define B_SZ  256

typedef _Float16 f16x8 __attribute__((ext_vector_type(8)));
typedef _Float16 h2    __attribute__((ext_vector_type(2)));
typedef float    f32x4 __attribute__((ext_vector_type(4)));

__device__ __forceinline__ float sigm(float x) { return 1.0f / (1.0f + __expf(-x)); }

__device__ __forceinline__ float fdot2(h2 a, h2 b, float c) {
#if __has_builtin(__builtin_amdgcn_fdot2)
    return __builtin_amdgcn_fdot2(a, b, c, false);
#else
    return c + (float)a.x * (float)b.x + (float)a.y * (float)b.y;
#endif
}

// quad_perm butterfly add: after both, all 4 lanes of the quad hold the quad sum.
__device__ __forceinline__ float qsum1(float x) {   // xor 1: [1,0,3,2] = 0xB1
    int yi = __builtin_amdgcn_update_dpp(0, __builtin_bit_cast(int, x), 0xB1, 0xF, 0xF, true);
    return x + __builtin_bit_cast(float, yi);
}
__device__ __forceinline__ float qsum2(float x) {   // xor 2: [2,3,0,1] = 0x4E
    int yi = __builtin_amdgcn_update_dpp(0, __builtin_bit_cast(int, x), 0x4E, 0xF, 0xF, true);
    return x + __builtin_bit_cast(float, yi);
}
__device__ __forceinline__ float qsum(float x) { return qsum2(qsum1(x)); }

// raw barrier: drain LDS only; global loads/stores stay in flight (no vmcnt(0) drain)
#define LBAR() do { \
    asm volatile("s_waitcnt lgkmcnt(0)" ::: "memory"); \
    __builtin_amdgcn_s_barrier(); \
    asm volatile("" ::: "memory"); \
} while (0)

// LDS tile byte offset with G4 XOR swizzle: row-major [128 rows][128 B]
__device__ __forceinline__ int swz(int row, int byte_in_row) {
    return row * 128 + (byte_in_row ^ ((row & 7) << 4));
}

// ---------------- pack: fp16 tables + packed fp16 weights + biases + h0/pred init --
__global__ void k_pack16(const float* __restrict__ W1, const float* __restrict__ Wd,
                         const float* __restrict__ W2, const float* __restrict__ W3,
                         const float* __restrict__ W4, const float* __restrict__ b2,
                         const float* __restrict__ b3, const float* __restrict__ b4,
                         const float* __restrict__ h0, const float* __restrict__ Wa,
                         const float* __restrict__ Eq, const float* __restrict__ Eut,
                         const float* __restrict__ Eit,
                         _Float16* __restrict__ Eq16, _Float16* __restrict__ Eut16,
                         _Float16* __restrict__ Eit16,
                         _Float16* __restrict__ Wld16, _Float16* __restrict__ Wz16,
                         h2* __restrict__ Wa16p,
                         float* __restrict__ bz, float* __restrict__ w1csum,
                         float* __restrict__ hcarry, float* __restrict__ pred)
{
    int idx0 = blockIdx.x * blockDim.x + threadIdx.x;
    int stride = gridDim.x * blockDim.x;
    for (int i = idx0; i < 10001 * 128; i += stride) Eq16[i] = (_Float16)Eq[i];
    for (int i = idx0; i < 1025 * 128; i += stride) Eut16[i] = (_Float16)Eut[i];
    for (int i = idx0; i < 1025 * 128; i += stride) Eit16[i] = (_Float16)Eit[i];
    for (int idx = idx0; idx < 256 * 256; idx += stride) {
        int c = idx >> 8, j = idx & 255;
        float v;
        if (c < 128) v = W1[c * 306 + j];
        else         v = (j < 128) ? Wd[(c - 128) * 128 + j] : 0.f;
        Wld16[idx] = (_Float16)v;
    }
    for (int idx = idx0; idx < 384 * 384; idx += stride) {
        int c = idx / 384, j = idx - c * 384;
        float v;
        if (c < 128)      v = W2[c * 512 + j];
        else if (c < 256) v = W3[(c - 128) * 512 + j];
        else              v = (j >= 128 && j < 256) ? W4[(c - 256) * 384 + 128 + j] : 0.f;
        Wz16[idx] = (_Float16)v;
    }
    for (int idx = idx0; idx < 128 * 64; idx += stride) {
        int c = idx >> 6, j = idx & 63;
        h2 v; v.x = (_Float16)Wa[c * 128 + 2 * j]; v.y = (_Float16)Wa[c * 128 + 2 * j + 1];
        Wa16p[idx] = v;
    }
    for (int idx = idx0; idx < 384; idx += stride)
        bz[idx] = (idx < 128) ? b2[idx] : (idx < 256 ? b3[idx - 128] : b4[idx - 256]);
    for (int idx = idx0; idx < 128; idx += stride) {
        float s = 0.f;
        for (int j = 0; j < 50; ++j) s += W1[idx * 306 + 256 + j];
        w1csum[idx] = s;
    }
    for (int idx = idx0; idx < 256 * 128; idx += stride) hcarry[idx] = h0[idx];
    for (int idx = idx0; idx < 256; idx += stride) pred[(size_t)idx * S_LEN] = 0.f;
}

// ---------------- disc: sigmoid(q . Wdisc + bdisc) * 10 (f32, full sequence) ------
__global__ __launch_bounds__(256) void k_disc(const int* __restrict__ qseq,
                                              const float* __restrict__ Eq,
                                              const float* __restrict__ Wdisc,
                                              const float* __restrict__ bdisc,
                                              float* __restrict__ disc)
{
    __shared__ float wd[128];
    __shared__ float bds;
    if (threadIdx.x < 128) wd[threadIdx.x] = Wdisc[threadIdx.x];
    if (threadIdx.x == 0) bds = bdisc[0];
    __syncthreads();
    int r = blockIdx.x * 64 + (threadIdx.x >> 2);
    int q4 = threadIdx.x & 3;
    const float* qe = Eq + (size_t)qseq[r] * 128 + q4 * 32;
    float s = 0.f;
#pragma unroll
    for (int j = 0; j < 32; ++j) s = fmaf(qe[j], wd[q4 * 32 + j], s);
    s += __shfl_xor(s, 1, 64);
    s += __shfl_xor(s, 2, 64);
    if (q4 == 0) disc[r] = sigm(s + bds) * 10.0f;
}

// ---------------- MFMA GEMM 1: learn (cb=0) / diff (cb=1); K=256 ------------------
__global__ __launch_bounds__(256) void k_mm_ld(
    const int* __restrict__ qseq, const int* __restrict__ utseq, const int* __restrict__ cseq,
    const _Float16* __restrict__ Eq16, const _Float16* __restrict__ Eut16,
    const _Float16* __restrict__ Wld16, const float* __restrict__ b1,
    const float* __restrict__ bd, const float* __restrict__ w1csum,
    _Float16* __restrict__ learn16, _Float16* __restrict__ diff16,
    int s_lo, int out_row0)
{
    __shared__ _Float16 As[128 * 64];
    __shared__ _Float16 Bs[128 * 64];
    __shared__ int   ridxq[128];
    __shared__ int   ridxut[128];
    __shared__ float rcorr[128];
    __shared__ float cS[128];
    __shared__ float c2S[128];

    const int tid = threadIdx.x;
    const int vr0 = blockIdx.x * 128;
    const int cb = blockIdx.y;

    if (tid < 128) {
        int vr = vr0 + tid;
        int b = vr & 255, s = s_lo + (vr >> 8);
        int rin = b * S_LEN + s;
        ridxq[tid] = qseq[rin];
        ridxut[tid] = utseq[rin];
        rcorr[tid] = (float)cseq[rin];
        cS[tid] = (cb == 0) ? w1csum[tid] : 0.f;
        c2S[tid] = (cb == 0) ? b1[tid] : bd[tid];
    }
    __syncthreads();

    const int wid = tid >> 6, lane = tid & 63;
    const int wr = wid >> 1, wc = wid & 1;
    const int lrow = lane & 15, lkg = lane >> 4;
    const int arow = tid >> 1, apart = tid & 1;

    f32x4 acc[4][4];
#pragma unroll
    for (int i = 0; i < 4; ++i)
#pragma unroll
        for (int j = 0; j < 4; ++j) acc[i][j] = (f32x4){0.f, 0.f, 0.f, 0.f};

    for (int kb = 0; kb < 4; ++kb) {
        int k0 = kb * 64;
        const _Float16* srcA = (k0 < 128)
            ? (Eq16 + (size_t)ridxq[arow] * 128 + k0 + apart * 32)
            : (Eut16 + (size_t)ridxut[arow] * 128 + (k0 - 128) + apart * 32);
        const _Float16* srcB = Wld16 + (size_t)(cb * 128 + arow) * 256 + k0 + apart * 32;
#pragma unroll
        for (int j = 0; j < 4; ++j) {
            float4 va = *(const float4*)(srcA + j * 8);
            float4 vb = *(const float4*)(srcB + j * 8);
            int boff = apart * 64 + j * 16;
            *(float4*)((char*)As + swz(arow, boff)) = va;
            *(float4*)((char*)Bs + swz(arow, boff)) = vb;
        }
        __syncthreads();
#pragma unroll
        for (int ks = 0; ks < 2; ++ks) {
            f16x8 af[4], bf[4];
#pragma unroll
            for (int f = 0; f < 4; ++f) {
                int ar = wr * 64 + f * 16 + lrow;
                af[f] = *(const f16x8*)((const char*)As + swz(ar, ks * 64 + lkg * 16));
                int br = wc * 64 + f * 16 + lrow;
                bf[f] = *(const f16x8*)((const char*)Bs + swz(br, ks * 64 + lkg * 16));
            }
#pragma unroll
            for (int fi = 0; fi < 4; ++fi)
#pragma unroll
                for (int fj = 0; fj < 4; ++fj)
                    acc[fi][fj] = __builtin_amdgcn_mfma_f32_16x16x32_f16(
                        af[fi], bf[fj], acc[fi][fj], 0, 0, 0);
        }
        __syncthreads();
    }

    if (cb == 0) {
#pragma unroll
        for (int fi = 0; fi < 4; ++fi) {
#pragma unroll
            for (int r = 0; r < 4; ++r) {
                int lr_ = wr * 64 + fi * 16 + (lane >> 4) * 4 + r;
                int grow = vr0 + out_row0 + lr_;
                float corr = rcorr[lr_];
#pragma unroll
                for (int fj = 0; fj < 4; ++fj) {
                    int col = wc * 64 + fj * 16 + (lane & 15);
                    float v = acc[fi][fj][r] + corr * cS[col] + c2S[col];
                    learn16[(size_t)grow * 128 + col] = (_Float16)v;
                }
            }
        }
    } else {
#pragma unroll
        for (int fi = 0; fi < 4; ++fi) {
#pragma unroll
            for (int r = 0; r < 4; ++r) {
                int lr_ = wr * 64 + fi * 16 + (lane >> 4) * 4 + r;
                int grow = vr0 + out_row0 + lr_;
#pragma unroll
                for (int fj = 0; fj < 4; ++fj) {
                    int col = wc * 64 + fj * 16 + (lane & 15);
                    float v = sigm(acc[fi][fj][r] + c2S[col]);
                    diff16[(size_t)grow * 128 + col] = (_Float16)v;
                }
            }
        }
    }
}

// ---------------- MFMA GEMM 2: U16[ur, cb*128..] , K=384 --------------------------
__global__ __launch_bounds__(256) void k_mm_u(
    const int* __restrict__ itseq, const _Float16* __restrict__ Eit16,
    const _Float16* __restrict__ learn16, const _Float16* __restrict__ Wz16,
    const float* __restrict__ bz, _Float16* __restrict__ U16, int t0)
{
    __shared__ _Float16 As[128 * 64];
    __shared__ _Float16 Bs[128 * 64];
    __shared__ int   itidx[128];
    __shared__ float bzS[128];

    const int tid = threadIdx.x;
    const int ur0 = blockIdx.x * 128;
    const int cb = blockIdx.y;
    const int t = t0 + (ur0 >> 8);
    const bool tzero = (t == 0);

    if (tid < 128) {
        int b = (ur0 + tid) & 255;
        itidx[tid] = itseq[b * S_LEN + t];
        bzS[tid] = bz[cb * 128 + tid];
    }
    __syncthreads();

    const int wid = tid >> 6, lane = tid & 63;
    const int wr = wid >> 1, wc = wid & 1;
    const int lrow = lane & 15, lkg = lane >> 4;
    const int arow = tid >> 1, apart = tid & 1;

    f32x4 acc[4][4];
#pragma unroll
    for (int i = 0; i < 4; ++i)
#pragma unroll
        for (int j = 0; j < 4; ++j) acc[i][j] = (f32x4){0.f, 0.f, 0.f, 0.f};

    for (int kb = 0; kb < 6; ++kb) {
        int k0 = kb * 64;
        int sec = k0 >> 7;
        int off = (k0 & 127) + apart * 32;
        const _Float16* srcA;
        if (sec == 0)      srcA = tzero ? nullptr : (learn16 + (size_t)(ur0 + arow) * 128 + off);
        else if (sec == 1) srcA = Eit16 + (size_t)itidx[arow] * 128 + off;
        else               srcA = learn16 + (size_t)(ur0 + arow + 256) * 128 + off;
        const _Float16* srcB = Wz16 + (size_t)(cb * 128 + arow) * 384 + k0 + apart * 32;
#pragma unroll
        for (int j = 0; j < 4; ++j) {
            float4 va;
            if (srcA) va = *(const float4*)(srcA + j * 8);
            else { va.x = va.y = va.z = va.w = 0.f; }
            float4 vb = *(const float4*)(srcB + j * 8);
            int boff = apart * 64 + j * 16;
            *(float4*)((char*)As + swz(arow, boff)) = va;
            *(float4*)((char*)Bs + swz(arow, boff)) = vb;
        }
        __syncthreads();
#pragma unroll
        for (int ks = 0; ks < 2; ++ks) {
            f16x8 af[4], bf[4];
#pragma unroll
            for (int f = 0; f < 4; ++f) {
                int ar = wr * 64 + f * 16 + lrow;
                af[f] = *(const f16x8*)((const char*)As + swz(ar, ks * 64 + lkg * 16));
                int br = wc * 64 + f * 16 + lrow;
                bf[f] = *(const f16x8*)((const char*)Bs + swz(br, ks * 64 + lkg * 16));
            }
#pragma unroll
            for (int fi = 0; fi < 4; ++fi)
#pragma unroll
                for (int fj = 0; fj < 4; ++fj)
                    acc[fi][fj] = __builtin_amdgcn_mfma_f32_16x16x32_f16(
                        af[fi], bf[fj], acc[fi][fj], 0, 0, 0);
        }
        __syncthreads();
    }

#pragma unroll
    for (int fi = 0; fi < 4; ++fi) {
#pragma unroll
        for (int r = 0; r < 4; ++r) {
            int lr_ = wr * 64 + fi * 16 + (lane >> 4) * 4 + r;
            int grow = ur0 + lr_;
#pragma unroll
            for (int fj = 0; fj < 4; ++fj) {
                int col = wc * 64 + fj * 16 + (lane & 15);
                float v = acc[fi][fj][r] + bzS[col];
                U16[(size_t)grow * 384 + cb * 128 + col] = (_Float16)v;
            }
        }
    }
}

// ---------------- scan v4: raw LDS-only barriers, DPP butterfly, split acc --------
__global__ __launch_bounds__(512) void k_scan(
    _Float16* __restrict__ U16, float* __restrict__ hcarry,
    const float* __restrict__ W2, const float* __restrict__ W3,
    const float* __restrict__ W4, int T_len)
{
    const int b = blockIdx.x;
    const int tid = threadIdx.x;
    const int k = tid >> 2;          // output channel 0..127
    const int q = tid & 3;           // j-quarter (32 elems = 16 pairs)

    // packed fp16 weight quarters in registers
    h2 w2h[16], w3h[16], w4h[16], w4l[16];
    {
        const float* p2 = W2 + k * 512 + 384 + q * 32;
        const float* p3 = W3 + k * 512 + 384 + q * 32;
        const float* p4h = W4 + k * 384 + q * 32;
        const float* p4l = W4 + k * 384 + 128 + q * 32;
#pragma unroll
        for (int j = 0; j < 16; ++j) {
            h2 a, c, d, e;
            a.x = (_Float16)p2[2 * j];  a.y = (_Float16)p2[2 * j + 1];
            c.x = (_Float16)p3[2 * j];  c.y = (_Float16)p3[2 * j + 1];
            d.x = (_Float16)p4h[2 * j]; d.y = (_Float16)p4h[2 * j + 1];
            e.x = (_Float16)p4l[2 * j]; e.y = (_Float16)p4l[2 * j + 1];
            w2h[j] = a; w3h[j] = c; w4h[j] = d; w4l[j] = e;
        }
    }

    __shared__ h2 hp16[64];     // packed fp16 h (128 halfs)
    __shared__ h2 lg16[64];     // packed fp16 LG

    float h_k = hcarry[b * 128 + k];   // f32 carried state, ALL lanes of the group
    if (tid < 64) {
        h2 v;
        v.x = (_Float16)hcarry[b * 128 + 2 * tid];
        v.y = (_Float16)hcarry[b * 128 + 2 * tid + 1];
        hp16[tid] = v;
    }
    __syncthreads();

    _Float16* Ub = U16 + (size_t)b * 384;
    // prefetch step 0
    float u2c = (float)Ub[k], u3c = (float)Ub[128 + k], u4c = (float)Ub[256 + k];

    for (int lt = 0; lt < T_len; ++lt) {
        // prefetch next step's u (stays in flight across raw barriers)
        float u2n = 0.f, u3n = 0.f, u4n = 0.f;
        if (lt + 1 < T_len) {
            const _Float16* Un = Ub + (size_t)(lt + 1) * (B_SZ * 384);
            u2n = (float)Un[k]; u3n = (float)Un[128 + k]; u4n = (float)Un[256 + k];
        }

        // ---- stage 1: s2,s3,s4 over h quarter (split accumulators)
        h2 hrq[16];
        {
            const h2* hq = hp16 + q * 16;
#pragma unroll
            for (int j = 0; j < 16; ++j) hrq[j] = hq[j];
        }
        float s2a = 0.f, s3a = 0.f, s4a = 0.f, s2b = 0.f, s3b = 0.f, s4b = 0.f;
#pragma unroll
        for (int j = 0; j < 8; ++j) {
            s2a = fdot2(hrq[j], w2h[j], s2a);
            s3a = fdot2(hrq[j], w3h[j], s3a);
            s4a = fdot2(hrq[j], w4h[j], s4a);
            s2b = fdot2(hrq[j + 8], w2h[j + 8], s2b);
            s3b = fdot2(hrq[j + 8], w3h[j + 8], s3b);
            s4b = fdot2(hrq[j + 8], w4h[j + 8], s4b);
        }
        float s2 = qsum(s2a + s2b);
        float s3 = qsum(s3a + s3b);
        float s4 = qsum(s4a + s4b);
        // all 4 lanes hold full sums -> all compute LG
        float LG_k = sigm(s3 + u3c) * sigm(2.f * (s2 + u2c));
        if (q == 0) ((_Float16*)lg16)[k] = (_Float16)LG_k;
        LBAR();

        // ---- stage 2: s4l over LG quarter; h update on all lanes
        h2 lrq[16];
        {
            const h2* lq = lg16 + q * 16;
#pragma unroll
            for (int j = 0; j < 16; ++j) lrq[j] = lq[j];
        }
        float s4la = 0.f, s4lb = 0.f;
#pragma unroll
        for (int j = 0; j < 8; ++j) {
            s4la = fdot2(lrq[j], w4l[j], s4la);
            s4lb = fdot2(lrq[j + 8], w4l[j + 8], s4lb);
        }
        float s4l = qsum(s4la + s4lb);
        float gf = sigm(s4 + s4l + u4c);
        h_k = LG_k + gf * h_k;
        if (q == 0) ((_Float16*)hp16)[k] = (_Float16)h_k;          // LDS for next step
        if (q == 1) Ub[(size_t)lt * (B_SZ * 384) + k] = (_Float16)h_k;  // global for k_post
        LBAR();

        u2c = u2n; u3c = u3n; u4c = u4n;
    }
    if (q == 0) hcarry[b * 128 + k] = h_k;
}

// ---------------- post: ability + y for all (t,b) in chunk, parallel --------------
__global__ __launch_bounds__(256) void k_post(
    const _Float16* __restrict__ U16, const _Float16* __restrict__ diff16,
    const float* __restrict__ disc, const h2* __restrict__ Wa16p,
    const float* __restrict__ ba, float* __restrict__ pred, int t0)
{
    __shared__ h2 WaS[128 * 64];     // swizzled: [c][j ^ (c&31)]
    __shared__ uint hS[4][64];       // per-wave h row (packed pairs)

    const int tid = threadIdx.x;
    const int w = tid >> 6, lane = tid & 63;

    for (int idx = tid; idx < 128 * 64; idx += 256) {
        int c = idx >> 6, j = idx & 63;
        WaS[(c << 6) + (j ^ (c & 31))] = Wa16p[idx];
    }
    __syncthreads();

    const int c1 = lane, c2 = lane + 64;
    const float ba1 = ba[c1], ba2 = ba[c2];
    const int x1 = c1 & 31, x2 = c2 & 31;

    for (int it = 0; it < 8; ++it) {
        int r = blockIdx.x * 32 + w * 8 + it;
        int b = r & 255, t = t0 + (r >> 8);
        const uint* hsrc = (const uint*)(U16 + (size_t)r * 384);
        hS[w][lane] = hsrc[lane];
        float d1 = (float)diff16[(size_t)(r + 512) * 128 + c1];
        float d2 = (float)diff16[(size_t)(r + 512) * 128 + c2];
        float g = disc[b * S_LEN + t + 1];
        __syncthreads();

        float dot1 = 0.f, dot2 = 0.f;
        const h2* hv = (const h2*)hS[w];
#pragma unroll
        for (int j = 0; j < 64; ++j) {
            h2 hj = hv[j];
            dot1 = fdot2(hj, WaS[(c1 << 6) + (j ^ x1)], dot1);
            dot2 = fdot2(hj, WaS[(c2 << 6) + (j ^ x2)], dot2);
        }
        float t1 = (sigm(dot1 + ba1) - d1) * d1;
        float t2 = (sigm(dot2 + ba2) - d2) * d2;
        float v = t1 + t2;
        v += __shfl_xor(v, 32, 64);
        v += __shfl_xor(v, 16, 64);
        v += __shfl_xor(v, 8, 64);
        v += __shfl_xor(v, 4, 64);
        v += __shfl_xor(v, 2, 64);
        v += __shfl_xor(v, 1, 64);
        if (lane == 0) pred[(size_t)b * S_LEN + t + 1] = sigm(g * v);
        __syncthreads();
    }
}

extern "C" void kernel_launch(void* const* d_in, const int* in_sizes, int n_in,
                              void* d_out, int out_size, void* d_ws, size_t ws_size,
                              hipStream_t stream)
{
    const int*   qseq  = (const int*)d_in[0];
    const int*   itseq = (const int*)d_in[1];
    const int*   utseq = (const int*)d_in[2];
    const int*   cseq  = (const int*)d_in[3];
    const float* h0    = (const float*)d_in[4];
    const float* Eq    = (const float*)d_in[5];
    const float* Eut   = (const float*)d_in[6];
    const float* Eit   = (const float*)d_in[7];
    const float* W1    = (const float*)d_in[8];
    const float* b1    = (const float*)d_in[9];
    const float* W2    = (const float*)d_in[10];
    const float* b2    = (const float*)d_in[11];
    const float* W3    = (const float*)d_in[12];
    const float* b3    = (const float*)d_in[13];
    const float* W4    = (const float*)d_in[14];
    const float* b4    = (const float*)d_in[15];
    const float* Wa    = (const float*)d_in[16];
    const float* ba    = (const float*)d_in[17];
    const float* Wd    = (const float*)d_in[18];
    const float* bd    = (const float*)d_in[19];
    const float* Wdisc = (const float*)d_in[20];
    const float* bdisc = (const float*)d_in[21];
    float* pred = (float*)d_out;

    // --- fixed-region layout ---
    char* p = (char*)d_ws;
    float* bz      = (float*)p;           p += 384 * 4;
    float* w1csum  = (float*)p;           p += 128 * 4;
    float* discb   = (float*)p;           p += 131072 * 4;
    float* hcarry  = (float*)p;           p += 32768 * 4;
    _Float16* Eq16  = (_Float16*)p;       p += 10001 * 128 * 2;
    _Float16* Eut16 = (_Float16*)p;       p += 1025 * 128 * 2;
    _Float16* Eit16 = (_Float16*)p;       p += 1025 * 128 * 2;
    _Float16* Wld16 = (_Float16*)p;       p += 256 * 256 * 2;
    _Float16* Wz16  = (_Float16*)p;       p += 384 * 384 * 2;
    h2*       Wa16p = (h2*)p;             p += 128 * 64 * 4;
    const size_t fixed_bytes = (size_t)(p - (char*)d_ws);

    int T_CH = 4;
    {
        const int cands[8] = {511, 256, 128, 64, 32, 16, 8, 4};
        for (int ci = 0; ci < 8; ++ci) {
            size_t T = (size_t)cands[ci];
            size_t need = fixed_bytes + (T + 2) * 131072 + T * 196608;
            if (need <= ws_size) { T_CH = cands[ci]; break; }
        }
    }
    _Float16* learn16 = (_Float16*)p;     p += (size_t)(T_CH + 2) * 65536 * 2;
    _Float16* diff16  = (_Float16*)p;     p += (size_t)(T_CH + 2) * 65536 * 2;
    _Float16* U16     = (_Float16*)p;

    k_pack16<<<2048, 256, 0, stream>>>(W1, Wd, W2, W3, W4, b2, b3, b4, h0, Wa,
                                       Eq, Eut, Eit, Eq16, Eut16, Eit16,
                                       Wld16, Wz16, Wa16p, bz, w1csum, hcarry, pred);
    k_disc<<<2048, 256, 0, stream>>>(qseq, Eq, Wdisc, bdisc, discb);

    for (int t0 = 0; t0 < S_LEN - 1; t0 += T_CH) {
        int T_len = S_LEN - 1 - t0; if (T_len > T_CH) T_len = T_CH;
        int s_lo = (t0 == 0) ? 0 : (t0 - 1);
        int s_hi = t0 + T_len + 1;
        int out_row0 = (s_lo - (t0 - 1)) * 256;
        k_mm_ld<<<dim3((s_hi - s_lo) * 2, 2), 256, 0, stream>>>(
            qseq, utseq, cseq, Eq16, Eut16, Wld16, b1, bd, w1csum,
            learn16, diff16, s_lo, out_row0);
        k_mm_u<<<dim3(T_len * 2, 3), 256, 0, stream>>>(
            itseq, Eit16, learn16, Wz16, bz, U16, t0);
        k_scan<<<256, 512, 0, stream>>>(U16, hcarry, W2, W3, W4, T_len);
        k_post<<<T_len * 8, 256, 0, stream>>>(U16, diff16, discb, Wa16p, ba, pred, t0);
    }
}